// Round 1
// baseline (560.553 us; speedup 1.0000x reference)
//
#include <hip/hip_runtime.h>
#include <stdint.h>

typedef __attribute__((ext_vector_type(8))) short bf16x8;   // 8 bf16 in 4 VGPRs
typedef __attribute__((ext_vector_type(4))) float f32x4;
typedef __attribute__((address_space(1))) void as1_void;
typedef __attribute__((address_space(3))) void as3_void;

#define D_MODEL 1024
#define SEQ     2048
#define BATCH   4
#define HEADS   16
#define HDIM    64

__device__ __forceinline__ ushort f2bf(float f) {
  union { float f; unsigned u; } v; v.f = f;
  unsigned u = v.u + 0x7fffu + ((v.u >> 16) & 1u);  // RNE
  return (ushort)(u >> 16);
}

__device__ __forceinline__ void gload_lds16(const void* g, void* l) {
  // width=16: emits global_load_lds_dwordx4; LDS dest = wave-uniform base + lane*16
  __builtin_amdgcn_global_load_lds((as1_void*)(uintptr_t)g, (as3_void*)l, 16, 0, 0);
}

// ---------- fp32 -> bf16 convert (X) ----------
__global__ void cvt_bf16_kernel(const float* __restrict__ in, ushort* __restrict__ out, int n4) {
  int i = blockIdx.x * blockDim.x + threadIdx.x;
  if (i >= n4) return;
  float4 f = reinterpret_cast<const float4*>(in)[i];
  ushort4 o;
  o.x = f2bf(f.x); o.y = f2bf(f.y); o.z = f2bf(f.z); o.w = f2bf(f.w);
  reinterpret_cast<ushort4*>(out)[i] = o;
}

// ---------- W[K][N] fp32 -> WT[N][K] bf16 (z selects which weight) ----------
__global__ void wtrans_kernel(const float* w0, const float* w1, const float* w2, const float* w3,
                              ushort* __restrict__ out) {
  const float* w = (blockIdx.z == 0) ? w0 : (blockIdx.z == 1) ? w1 : (blockIdx.z == 2) ? w2 : w3;
  ushort* o = out + (size_t)blockIdx.z * D_MODEL * D_MODEL;
  __shared__ float tile[32][33];
  int tx = threadIdx.x, ty = threadIdx.y;
  int x = blockIdx.x * 32 + tx;   // n
  int y0 = blockIdx.y * 32;       // k
  #pragma unroll
  for (int i = ty; i < 32; i += 8)
    tile[i][tx] = w[(size_t)(y0 + i) * D_MODEL + x];
  __syncthreads();
  #pragma unroll
  for (int i = ty; i < 32; i += 8)
    o[(size_t)(blockIdx.x * 32 + i) * D_MODEL + y0 + tx] = f2bf(tile[tx][i]);
}

// ---------- m97-style GEMM: C[M][N] = A[M][K] @ BT[N][K]^T + bias ----------
// 128x128 tile, BK=32, 4 waves of 64x64, global_load_lds staging (packed 64B rows)
template <typename OutT>
__global__ __launch_bounds__(256) void gemm_bt(const ushort* __restrict__ A, const ushort* __restrict__ BT,
                                               const float* __restrict__ bias, OutT* __restrict__ C,
                                               int M, int N, int K) {
  __shared__ __align__(16) ushort As[128 * 32];
  __shared__ __align__(16) ushort Bs[128 * 32];
  const int tid  = threadIdx.x;
  const int w    = tid >> 6;
  const int lane = tid & 63;
  const int lo   = lane & 15, quad = lane >> 4;
  const int m0 = blockIdx.y * 128, n0 = blockIdx.x * 128;
  const int ra = lane >> 2;          // row within 16-row staging group
  const int ca = (lane & 3) * 8;     // elem col within BK=32
  const int wm = (w & 1) * 64, wn = (w >> 1) * 64;

  f32x4 acc[4][4];
  #pragma unroll
  for (int i = 0; i < 4; ++i)
    #pragma unroll
    for (int j = 0; j < 4; ++j) acc[i][j] = {0.f, 0.f, 0.f, 0.f};

  for (int k0 = 0; k0 < K; k0 += 32) {
    #pragma unroll
    for (int i = 0; i < 2; ++i) {
      const int j = w * 2 + i;   // 0..7 staging instruction slot (wave-uniform)
      gload_lds16(A  + (size_t)(m0 + j * 16 + ra) * K + k0 + ca, &As[j * 512]);
      gload_lds16(BT + (size_t)(n0 + j * 16 + ra) * K + k0 + ca, &Bs[j * 512]);
    }
    __syncthreads();   // compiler emits vmcnt(0) drain before s_barrier
    bf16x8 af[4], bfv[4];
    #pragma unroll
    for (int mi = 0; mi < 4; ++mi) af[mi]  = *(const bf16x8*)&As[(wm + mi * 16 + lo) * 32 + quad * 8];
    #pragma unroll
    for (int ni = 0; ni < 4; ++ni) bfv[ni] = *(const bf16x8*)&Bs[(wn + ni * 16 + lo) * 32 + quad * 8];
    #pragma unroll
    for (int mi = 0; mi < 4; ++mi)
      #pragma unroll
      for (int ni = 0; ni < 4; ++ni)
        acc[mi][ni] = __builtin_amdgcn_mfma_f32_16x16x32_bf16(af[mi], bfv[ni], acc[mi][ni], 0, 0, 0);
    __syncthreads();
  }

  #pragma unroll
  for (int ni = 0; ni < 4; ++ni) {
    const int col = n0 + wn + ni * 16 + lo;
    const float bv = bias[col];
    #pragma unroll
    for (int mi = 0; mi < 4; ++mi) {
      #pragma unroll
      for (int r = 0; r < 4; ++r) {
        const int row = m0 + wm + mi * 16 + quad * 4 + r;  // C/D layout: row=quad*4+r, col=lane&15
        float v = acc[mi][ni][r] + bv;
        if constexpr (sizeof(OutT) == 2) C[(size_t)row * N + col] = (OutT)f2bf(v);
        else                             C[(size_t)row * N + col] = v;
      }
    }
  }
}

// ---------- flash attention: block = (b, h, 64 q-rows), wave = 16 q-rows ----------
__global__ __launch_bounds__(256) void attn_kernel(const ushort* __restrict__ Qg, const ushort* __restrict__ Kg,
                                                   const ushort* __restrict__ Vg, ushort* __restrict__ Og) {
  constexpr int KP = 72;  // Ks pitch elems: 144B rows, 16B aligned, 2-way max conflict
  constexpr int VP = 40;  // Vt pitch elems: 80B rows
  constexpr int PP = 40;  // Ps pitch elems
  __shared__ __align__(16) ushort Ks[32 * KP];      // K chunk [32 keys][64 d]
  __shared__ __align__(16) ushort Vt[HDIM * VP];    // V^T     [64 d][32 keys]
  __shared__ __align__(16) ushort Ps[4][16 * PP];   // per-wave P [16 q][32 keys]

  const int tid  = threadIdx.x;
  const int w    = tid >> 6, lane = tid & 63;
  const int lo   = lane & 15, quad = lane >> 4;
  const int qb = blockIdx.x, h = blockIdx.y, b = blockIdx.z;

  // Q fragments (A-operand layout: m=lane&15, k=quad*8+j), kept in regs for the whole kernel
  const size_t rowQ = (size_t)(b * SEQ + qb * 64 + w * 16 + lo) * D_MODEL + h * HDIM;
  const bf16x8 qf0 = *(const bf16x8*)(Qg + rowQ + quad * 8);
  const bf16x8 qf1 = *(const bf16x8*)(Qg + rowQ + 32 + quad * 8);

  const ushort* Kb = Kg + (size_t)(b * SEQ) * D_MODEL + h * HDIM;
  const ushort* Vb = Vg + (size_t)(b * SEQ) * D_MODEL + h * HDIM;

  f32x4 acc[4];
  #pragma unroll
  for (int t = 0; t < 4; ++t) acc[t] = {0.f, 0.f, 0.f, 0.f};
  float mr[4] = {-1e30f, -1e30f, -1e30f, -1e30f};
  float lr[4] = {0.f, 0.f, 0.f, 0.f};

  const int kkey = tid >> 3, kdg = (tid & 7) * 8;     // K staging: 32 keys x 64 d
  const int vkey = tid & 31, vd = (tid >> 5) * 8;     // V staging (transposed write)
  const float scale = 1.0f / 32.0f;                   // reference scale = HDIM/2 (sic)

  for (int c = 0; c < SEQ / 32; ++c) {
    __syncthreads();  // previous chunk fully consumed
    *(uint4*)&Ks[kkey * KP + kdg] = *(const uint4*)(Kb + (size_t)(c * 32 + kkey) * D_MODEL + kdg);
    {
      uint4 raw = *(const uint4*)(Vb + (size_t)(c * 32 + vkey) * D_MODEL + vd);
      const ushort* rv = (const ushort*)&raw;
      #pragma unroll
      for (int i = 0; i < 8; ++i) Vt[(vd + i) * VP + vkey] = rv[i];
    }
    __syncthreads();

    // S tiles: two 16-key subtiles, each contracted over d=64 in 2 MFMAs
    f32x4 s0 = {0.f, 0.f, 0.f, 0.f}, s1 = {0.f, 0.f, 0.f, 0.f};
    {
      const ushort* kr = &Ks[lo * KP];
      bf16x8 ka = *(const bf16x8*)(kr + quad * 8);
      bf16x8 kb = *(const bf16x8*)(kr + 32 + quad * 8);
      s0 = __builtin_amdgcn_mfma_f32_16x16x32_bf16(qf0, ka, s0, 0, 0, 0);
      s0 = __builtin_amdgcn_mfma_f32_16x16x32_bf16(qf1, kb, s0, 0, 0, 0);
      kr = &Ks[(16 + lo) * KP];
      ka = *(const bf16x8*)(kr + quad * 8);
      kb = *(const bf16x8*)(kr + 32 + quad * 8);
      s1 = __builtin_amdgcn_mfma_f32_16x16x32_bf16(qf0, ka, s1, 0, 0, 0);
      s1 = __builtin_amdgcn_mfma_f32_16x16x32_bf16(qf1, kb, s1, 0, 0, 0);
    }

    // online softmax (rows = quad*4+r; reduce across the 16 lanes of this quad)
    float p0[4], p1[4], mx[4], al[4], sum[4];
    #pragma unroll
    for (int r = 0; r < 4; ++r) {
      p0[r] = s0[r] * scale; p1[r] = s1[r] * scale;
      mx[r] = fmaxf(p0[r], p1[r]);
    }
    #pragma unroll
    for (int off = 8; off; off >>= 1)
      #pragma unroll
      for (int r = 0; r < 4; ++r) mx[r] = fmaxf(mx[r], __shfl_xor(mx[r], off));
    #pragma unroll
    for (int r = 0; r < 4; ++r) {
      float mn = fmaxf(mr[r], mx[r]);
      al[r] = __expf(mr[r] - mn);
      mr[r] = mn;
      p0[r] = __expf(p0[r] - mn);
      p1[r] = __expf(p1[r] - mn);
      sum[r] = p0[r] + p1[r];
    }
    #pragma unroll
    for (int off = 8; off; off >>= 1)
      #pragma unroll
      for (int r = 0; r < 4; ++r) sum[r] += __shfl_xor(sum[r], off);
    #pragma unroll
    for (int r = 0; r < 4; ++r) lr[r] = lr[r] * al[r] + sum[r];
    #pragma unroll
    for (int t = 0; t < 4; ++t)
      #pragma unroll
      for (int r = 0; r < 4; ++r) acc[t][r] *= al[r];

    // P: C-layout -> A-layout via per-wave LDS round-trip (m120 pattern)
    ushort* pw = Ps[w];
    #pragma unroll
    for (int r = 0; r < 4; ++r) {
      pw[(quad * 4 + r) * PP + lo]      = f2bf(p0[r]);
      pw[(quad * 4 + r) * PP + 16 + lo] = f2bf(p1[r]);
    }
    __asm__ volatile("s_waitcnt lgkmcnt(0)" ::: "memory");  // wave-local write->read ordering

    bf16x8 pf = *(const bf16x8*)&pw[lo * PP + quad * 8];
    #pragma unroll
    for (int t = 0; t < 4; ++t) {
      bf16x8 vf = *(const bf16x8*)&Vt[(t * 16 + lo) * VP + quad * 8];
      acc[t] = __builtin_amdgcn_mfma_f32_16x16x32_bf16(pf, vf, acc[t], 0, 0, 0);
    }
  }

  // epilogue: normalize rows and store bf16
  float inv[4];
  #pragma unroll
  for (int r = 0; r < 4; ++r) inv[r] = 1.0f / lr[r];
  const int orow = b * SEQ + qb * 64 + w * 16 + quad * 4;
  #pragma unroll
  for (int t = 0; t < 4; ++t)
    #pragma unroll
    for (int r = 0; r < 4; ++r)
      Og[(size_t)(orow + r) * D_MODEL + h * HDIM + t * 16 + lo] = f2bf(acc[t][r] * inv[r]);
}

extern "C" void kernel_launch(void* const* d_in, const int* in_sizes, int n_in,
                              void* d_out, int out_size, void* d_ws, size_t ws_size,
                              hipStream_t stream) {
  const float* X  = (const float*)d_in[0];
  const float* Wq = (const float*)d_in[1];
  const float* bq = (const float*)d_in[2];
  const float* Wk = (const float*)d_in[3];
  const float* bk = (const float*)d_in[4];
  const float* Wv = (const float*)d_in[5];
  const float* bv = (const float*)d_in[6];
  const float* Wo = (const float*)d_in[7];
  const float* bo = (const float*)d_in[8];
  float* out = (float*)d_out;
  char* ws = (char*)d_ws;

  // workspace layout (bytes): Xbf 16M | WT 4x2M | Q 16M | K 16M | V 16M | O 16M = 88 MB
  ushort* Xb = (ushort*)(ws);
  ushort* WT = (ushort*)(ws + 16777216);
  ushort* Qb = (ushort*)(ws + 25165824);
  ushort* Kb = (ushort*)(ws + 41943040);
  ushort* Vb = (ushort*)(ws + 58720256);
  ushort* Ob = (ushort*)(ws + 75497472);
  const int WSTRIDE = D_MODEL * D_MODEL;  // elems per transposed weight

  // 1) convert X to bf16
  const int n4 = BATCH * SEQ * D_MODEL / 4;  // 2097152
  cvt_bf16_kernel<<<n4 / 256, 256, 0, stream>>>(X, Xb, n4);

  // 2) transpose+convert all four weights
  wtrans_kernel<<<dim3(32, 32, 4), dim3(32, 8), 0, stream>>>(Wq, Wk, Wv, Wo, WT);

  // 3) Q/K/V projections (bf16 out)
  const int M = BATCH * SEQ;  // 8192
  gemm_bt<ushort><<<dim3(8, 64), 256, 0, stream>>>(Xb, WT,               bq, Qb, M, D_MODEL, D_MODEL);
  gemm_bt<ushort><<<dim3(8, 64), 256, 0, stream>>>(Xb, WT + 1 * WSTRIDE, bk, Kb, M, D_MODEL, D_MODEL);
  gemm_bt<ushort><<<dim3(8, 64), 256, 0, stream>>>(Xb, WT + 2 * WSTRIDE, bv, Vb, M, D_MODEL, D_MODEL);

  // 4) fused flash attention (no S materialization)
  attn_kernel<<<dim3(SEQ / 64, HEADS, BATCH), 256, 0, stream>>>(Qb, Kb, Vb, Ob);

  // 5) output projection (fp32 out + bias)
  gemm_bt<float><<<dim3(8, 64), 256, 0, stream>>>(Ob, WT + 3 * WSTRIDE, bo, out, M, D_MODEL, D_MODEL);
}

// Round 2
// 301.612 us; speedup vs baseline: 1.8585x; 1.8585x over previous
//
#include <hip/hip_runtime.h>
#include <stdint.h>

typedef __attribute__((ext_vector_type(8))) short bf16x8;   // 8 bf16 in 4 VGPRs
typedef __attribute__((ext_vector_type(4))) float f32x4;
typedef __attribute__((address_space(1))) void as1_void;
typedef __attribute__((address_space(3))) void as3_void;

#define D_MODEL 1024
#define SEQ     2048
#define BATCH   4
#define HEADS   16
#define HDIM    64
#define PPITCH  72   // P row pitch in elems (144B: 16B-aligned, bank-uniform)

__device__ __forceinline__ ushort f2bf(float f) {
  union { float f; unsigned u; } v; v.f = f;
  unsigned u = v.u + 0x7fffu + ((v.u >> 16) & 1u);  // RNE
  return (ushort)(u >> 16);
}

__device__ __forceinline__ void gload_lds16(const void* g, void* l) {
  // width=16: emits global_load_lds_dwordx4; LDS dest = wave-uniform base + lane*16
  __builtin_amdgcn_global_load_lds((as1_void*)(uintptr_t)g, (as3_void*)l, 16, 0, 0);
}

// ---------- fp32 -> bf16 convert (X) ----------
__global__ void cvt_bf16_kernel(const float* __restrict__ in, ushort* __restrict__ out, int n4) {
  int i = blockIdx.x * blockDim.x + threadIdx.x;
  if (i >= n4) return;
  float4 f = reinterpret_cast<const float4*>(in)[i];
  ushort4 o;
  o.x = f2bf(f.x); o.y = f2bf(f.y); o.z = f2bf(f.z); o.w = f2bf(f.w);
  reinterpret_cast<ushort4*>(out)[i] = o;
}

// ---------- W[K][N] fp32 -> WT[N][K] bf16 (z selects which weight) ----------
__global__ void wtrans_kernel(const float* w0, const float* w1, const float* w2, const float* w3,
                              ushort* __restrict__ out) {
  const float* w = (blockIdx.z == 0) ? w0 : (blockIdx.z == 1) ? w1 : (blockIdx.z == 2) ? w2 : w3;
  ushort* o = out + (size_t)blockIdx.z * D_MODEL * D_MODEL;
  __shared__ float tile[32][33];
  int tx = threadIdx.x, ty = threadIdx.y;
  int x = blockIdx.x * 32 + tx;   // n
  int y0 = blockIdx.y * 32;       // k
  #pragma unroll
  for (int i = ty; i < 32; i += 8)
    tile[i][tx] = w[(size_t)(y0 + i) * D_MODEL + x];
  __syncthreads();
  #pragma unroll
  for (int i = ty; i < 32; i += 8)
    o[(size_t)(blockIdx.x * 32 + i) * D_MODEL + y0 + tx] = f2bf(tile[tx][i]);
}

// ---------- concat bq|bk|bv into one 3072 bias ----------
__global__ void biascat_kernel(const float* __restrict__ bq, const float* __restrict__ bk,
                               const float* __restrict__ bv, float* __restrict__ out) {
  int i = blockIdx.x * 256 + threadIdx.x;
  out[i] = (i < 1024) ? bq[i] : (i < 2048) ? bk[i - 1024] : bv[i - 2048];
}

// ---------- V (cols 2048..3071 of QKV) -> Vt[b][h][d][S], keys permuted per 64-chunk ----------
// Vt col (chunk*64 + c) holds key chunk*64 + (c&3)*16 + (c>>2)
__global__ void vtrans_kernel(const ushort* __restrict__ QKV, ushort* __restrict__ Vt) {
  __shared__ ushort tile[64][PPITCH];
  const int t = threadIdx.x;
  const int ck = blockIdx.x, h = blockIdx.y, b = blockIdx.z;
  {
    int key = t >> 2, ds = (t & 3) * 16;
    const ushort* src = QKV + (size_t)(b * SEQ + ck * 64 + key) * 3072 + 2048 + h * HDIM + ds;
    *(uint4*)&tile[key][ds]     = *(const uint4*)src;
    *(uint4*)&tile[key][ds + 8] = *(const uint4*)(src + 8);
  }
  __syncthreads();
  {
    int d = t >> 2, cg = (t & 3) * 16;
    ushort outv[16];
    #pragma unroll
    for (int i = 0; i < 16; ++i) {
      int c = cg + i;
      int a = (c & 3) * 16 + (c >> 2);
      outv[i] = tile[a][d];
    }
    ushort* dst = Vt + (size_t)((b * HEADS + h) * HDIM + d) * SEQ + ck * 64 + cg;
    *(uint4*)dst       = *(uint4*)&outv[0];
    *(uint4*)(dst + 8) = *(uint4*)&outv[8];
  }
}

// ---------- m97-style GEMM: C[M][N] = A[M][K] @ BT[N][K]^T + bias ----------
template <typename OutT>
__global__ __launch_bounds__(256) void gemm_bt(const ushort* __restrict__ A, const ushort* __restrict__ BT,
                                               const float* __restrict__ bias, OutT* __restrict__ C,
                                               int M, int N, int K) {
  __shared__ __align__(16) ushort As[128 * 32];
  __shared__ __align__(16) ushort Bs[128 * 32];
  const int tid  = threadIdx.x;
  const int w    = tid >> 6;
  const int lane = tid & 63;
  const int lo   = lane & 15, quad = lane >> 4;
  const int m0 = blockIdx.y * 128, n0 = blockIdx.x * 128;
  const int ra = lane >> 2;
  const int ca = (lane & 3) * 8;
  const int wm = (w & 1) * 64, wn = (w >> 1) * 64;

  f32x4 acc[4][4];
  #pragma unroll
  for (int i = 0; i < 4; ++i)
    #pragma unroll
    for (int j = 0; j < 4; ++j) acc[i][j] = {0.f, 0.f, 0.f, 0.f};

  for (int k0 = 0; k0 < K; k0 += 32) {
    #pragma unroll
    for (int i = 0; i < 2; ++i) {
      const int j = w * 2 + i;
      gload_lds16(A  + (size_t)(m0 + j * 16 + ra) * K + k0 + ca, &As[j * 512]);
      gload_lds16(BT + (size_t)(n0 + j * 16 + ra) * K + k0 + ca, &Bs[j * 512]);
    }
    __syncthreads();
    bf16x8 af[4], bfv[4];
    #pragma unroll
    for (int mi = 0; mi < 4; ++mi) af[mi]  = *(const bf16x8*)&As[(wm + mi * 16 + lo) * 32 + quad * 8];
    #pragma unroll
    for (int ni = 0; ni < 4; ++ni) bfv[ni] = *(const bf16x8*)&Bs[(wn + ni * 16 + lo) * 32 + quad * 8];
    #pragma unroll
    for (int mi = 0; mi < 4; ++mi)
      #pragma unroll
      for (int ni = 0; ni < 4; ++ni)
        acc[mi][ni] = __builtin_amdgcn_mfma_f32_16x16x32_bf16(af[mi], bfv[ni], acc[mi][ni], 0, 0, 0);
    __syncthreads();
  }

  #pragma unroll
  for (int ni = 0; ni < 4; ++ni) {
    const int col = n0 + wn + ni * 16 + lo;
    const float bv = bias[col];
    #pragma unroll
    for (int mi = 0; mi < 4; ++mi) {
      #pragma unroll
      for (int r = 0; r < 4; ++r) {
        const int row = m0 + wm + mi * 16 + quad * 4 + r;
        float v = acc[mi][ni][r] + bv;
        if constexpr (sizeof(OutT) == 2) C[(size_t)row * N + col] = (OutT)f2bf(v);
        else                             C[(size_t)row * N + col] = v;
      }
    }
  }
}

// ---------- flash attention: block = 256 q rows, wave = 64 q rows (4 qg x 16), 64-key chunks ----------
__global__ __launch_bounds__(256, 2) void attn_kernel(const ushort* __restrict__ QKV,
                                                      const ushort* __restrict__ Vt,
                                                      ushort* __restrict__ Og) {
  __shared__ __align__(16) ushort Ks[64 * 64];                 // [key][64 d], seg-swizzled
  __shared__ __align__(16) ushort Vs[64 * 64];                 // [d][64 key], seg-swizzled
  __shared__ __align__(16) ushort Ps[4 * 4 * 16 * PPITCH];     // [w][qg][16 rows][72]

  const int tid  = threadIdx.x;
  const int w    = tid >> 6, lane = tid & 63;
  const int lo   = lane & 15, quad = lane >> 4;
  const int h = blockIdx.y, b = blockIdx.z;
  const int qbase = blockIdx.x * 256 + w * 64;
  const float C = 1.44269504089f / 32.0f;   // exp(s/32) = exp2(s*C); ref scale = HDIM/2

  // Q fragments (A-layout: m=lo, k=quad*8+j), held whole kernel
  bf16x8 qf[4][2];
  #pragma unroll
  for (int qg = 0; qg < 4; ++qg) {
    const ushort* qp = QKV + (size_t)(b * SEQ + qbase + qg * 16 + lo) * 3072 + h * HDIM;
    qf[qg][0] = *(const bf16x8*)(qp + quad * 8);
    qf[qg][1] = *(const bf16x8*)(qp + 32 + quad * 8);
  }

  f32x4 acc[4][4];
  #pragma unroll
  for (int qg = 0; qg < 4; ++qg)
    #pragma unroll
    for (int t = 0; t < 4; ++t) acc[qg][t] = {0.f, 0.f, 0.f, 0.f};
  float lsum[4][4];
  #pragma unroll
  for (int qg = 0; qg < 4; ++qg)
    #pragma unroll
    for (int r = 0; r < 4; ++r) lsum[qg][r] = 0.f;

  const int swz = (lo & 7);   // read-side seg swizzle key

  for (int ck = 0; ck < SEQ / 64; ++ck) {
    __syncthreads();   // previous chunk fully consumed
    #pragma unroll
    for (int i = 0; i < 2; ++i) {
      const int c16 = (w * 2 + i) * 64 + lane;
      const int r = c16 >> 3, ps = c16 & 7;
      const int gs = ps ^ (r & 7);
      gload_lds16(QKV + (size_t)(b * SEQ + ck * 64 + r) * 3072 + 1024 + h * HDIM + gs * 8,
                  &Ks[(w * 2 + i) * 512]);
      gload_lds16(Vt + (size_t)((b * HEADS + h) * HDIM + r) * SEQ + ck * 64 + gs * 8,
                  &Vs[(w * 2 + i) * 512]);
    }
    __syncthreads();

    // --- phase A: scores + exp + P write ---
    bf16x8 kf[4][2];
    #pragma unroll
    for (int sub = 0; sub < 4; ++sub)
      #pragma unroll
      for (int hh = 0; hh < 2; ++hh)
        kf[sub][hh] = *(const bf16x8*)&Ks[(sub * 16 + lo) * 64 + (((hh * 4 + quad) ^ swz) * 8)];

    #pragma unroll
    for (int qg = 0; qg < 4; ++qg) {
      f32x4 s[4];
      #pragma unroll
      for (int sub = 0; sub < 4; ++sub) s[sub] = {0.f, 0.f, 0.f, 0.f};
      #pragma unroll
      for (int hh = 0; hh < 2; ++hh)
        #pragma unroll
        for (int sub = 0; sub < 4; ++sub)
          s[sub] = __builtin_amdgcn_mfma_f32_16x16x32_bf16(qf[qg][hh], kf[sub][hh], s[sub], 0, 0, 0);

      ushort* prow = &Ps[(w * 4 + qg) * 16 * PPITCH];
      #pragma unroll
      for (int r = 0; r < 4; ++r) {
        float p0 = __builtin_amdgcn_exp2f(s[0][r] * C);
        float p1 = __builtin_amdgcn_exp2f(s[1][r] * C);
        float p2 = __builtin_amdgcn_exp2f(s[2][r] * C);
        float p3 = __builtin_amdgcn_exp2f(s[3][r] * C);
        lsum[qg][r] += (p0 + p1) + (p2 + p3);
        // truncating bf16 pack: col lo*4+sub holds key sub*16+lo (matches Vt permutation)
        uint d0 = __builtin_amdgcn_perm(__float_as_uint(p1), __float_as_uint(p0), 0x07060302);
        uint d1 = __builtin_amdgcn_perm(__float_as_uint(p3), __float_as_uint(p2), 0x07060302);
        uint2 pk; pk.x = d0; pk.y = d1;
        *(uint2*)&prow[(quad * 4 + r) * PPITCH + lo * 4] = pk;
      }
    }
    __asm__ volatile("s_waitcnt lgkmcnt(0)" ::: "memory");   // wave-local P write->read

    // --- phase B: PV ---
    bf16x8 pf[4][2];
    #pragma unroll
    for (int qg = 0; qg < 4; ++qg)
      #pragma unroll
      for (int hh = 0; hh < 2; ++hh)
        pf[qg][hh] = *(const bf16x8*)&Ps[((w * 4 + qg) * 16 + lo) * PPITCH + hh * 32 + quad * 8];

    #pragma unroll
    for (int hh = 0; hh < 2; ++hh)
      #pragma unroll
      for (int t = 0; t < 4; ++t) {
        bf16x8 vf = *(const bf16x8*)&Vs[(t * 16 + lo) * 64 + (((hh * 4 + quad) ^ swz) * 8)];
        #pragma unroll
        for (int qg = 0; qg < 4; ++qg)
          acc[qg][t] = __builtin_amdgcn_mfma_f32_16x16x32_bf16(pf[qg][hh], vf, acc[qg][t], 0, 0, 0);
      }
  }

  // --- epilogue: reduce row sums across the 16 lanes of each quad, normalize, store ---
  float linv[4][4];
  #pragma unroll
  for (int qg = 0; qg < 4; ++qg)
    #pragma unroll
    for (int r = 0; r < 4; ++r) {
      float v = lsum[qg][r];
      v += __shfl_xor(v, 1); v += __shfl_xor(v, 2);
      v += __shfl_xor(v, 4); v += __shfl_xor(v, 8);
      linv[qg][r] = 1.0f / v;
    }
  #pragma unroll
  for (int qg = 0; qg < 4; ++qg)
    #pragma unroll
    for (int t = 0; t < 4; ++t)
      #pragma unroll
      for (int r = 0; r < 4; ++r)
        Og[(size_t)(b * SEQ + qbase + qg * 16 + quad * 4 + r) * D_MODEL + h * HDIM + t * 16 + lo] =
            f2bf(acc[qg][t][r] * linv[qg][r]);
}

extern "C" void kernel_launch(void* const* d_in, const int* in_sizes, int n_in,
                              void* d_out, int out_size, void* d_ws, size_t ws_size,
                              hipStream_t stream) {
  const float* X  = (const float*)d_in[0];
  const float* Wq = (const float*)d_in[1];
  const float* bq = (const float*)d_in[2];
  const float* Wk = (const float*)d_in[3];
  const float* bk = (const float*)d_in[4];
  const float* Wv = (const float*)d_in[5];
  const float* bv = (const float*)d_in[6];
  const float* Wo = (const float*)d_in[7];
  const float* bo = (const float*)d_in[8];
  float* out = (float*)d_out;
  char* ws = (char*)d_ws;

  // workspace (88 MB, same footprint as the verified round-0 layout):
  //   [0,16M)   Xb (bf16 X)  -- later reused as Vt (Xb dead after QKV GEMM)
  //   [16,24M)  WT (4x bf16 transposed weights, q|k|v|o)
  //   [24,72M)  QKV bf16 [8192][3072]
  //   [72,88M)  O bf16 [8192][1024]; first 12KB transiently holds biascat (dead before attn writes O)
  ushort* Xb   = (ushort*)(ws);
  ushort* Vtb  = (ushort*)(ws);                    // aliases Xb (sequential lifetimes)
  ushort* WT   = (ushort*)(ws + 16777216);
  ushort* QKVb = (ushort*)(ws + 25165824);
  ushort* Ob   = (ushort*)(ws + 75497472);
  float*  bcat = (float*)(ws + 75497472);          // aliases O head (consumed before attn)
  const int WSTRIDE = D_MODEL * D_MODEL;

  const int n4 = BATCH * SEQ * D_MODEL / 4;
  cvt_bf16_kernel<<<n4 / 256, 256, 0, stream>>>(X, Xb, n4);
  wtrans_kernel<<<dim3(32, 32, 4), dim3(32, 8), 0, stream>>>(Wq, Wk, Wv, Wo, WT);
  biascat_kernel<<<12, 256, 0, stream>>>(bq, bk, bv, bcat);

  // fused QKV projection: [8192,1024] @ [1024,3072] -> QKV bf16
  const int M = BATCH * SEQ;
  gemm_bt<ushort><<<dim3(24, 64), 256, 0, stream>>>(Xb, WT, bcat, QKVb, M, 3 * D_MODEL, D_MODEL);

  // V -> Vt (transposed + per-chunk key permutation)
  vtrans_kernel<<<dim3(SEQ / 64, HEADS, BATCH), 256, 0, stream>>>(QKVb, Vtb);

  // flash attention
  attn_kernel<<<dim3(SEQ / 256, HEADS, BATCH), 256, 0, stream>>>(QKVb, Vtb, Ob);

  // output projection (fp32 out + bias)
  gemm_bt<float><<<dim3(8, 64), 256, 0, stream>>>(Ob, WT + 3 * WSTRIDE, bo, out, M, D_MODEL, D_MODEL);
}

// Round 3
// 295.654 us; speedup vs baseline: 1.8960x; 1.0202x over previous
//
#include <hip/hip_runtime.h>
#include <stdint.h>

typedef __attribute__((ext_vector_type(8))) short bf16x8;   // 8 bf16 in 4 VGPRs
typedef __attribute__((ext_vector_type(4))) float f32x4;
typedef __attribute__((address_space(1))) void as1_void;
typedef __attribute__((address_space(3))) void as3_void;

#define D_MODEL 1024
#define SEQ     2048
#define BATCH   4
#define HEADS   16
#define HDIM    64
#define TPITCH  72   // vtrans LDS tile pitch

// softmax scale: exp(s/32) = exp2(s * log2e/32); folded into Wq/bq at prep time
#define QSCALE 0.045084220029218407f

__device__ __forceinline__ ushort f2bf(float f) {
  union { float f; unsigned u; } v; v.f = f;
  unsigned u = v.u + 0x7fffu + ((v.u >> 16) & 1u);  // RNE
  return (ushort)(u >> 16);
}

__device__ __forceinline__ void gload_lds16(const void* g, void* l) {
  // width=16: emits global_load_lds_dwordx4; LDS dest = wave-uniform base + lane*16
  __builtin_amdgcn_global_load_lds((as1_void*)(uintptr_t)g, (as3_void*)l, 16, 0, 0);
}

// pack 8 floats -> bf16x8 (truncation) via v_perm; elem order a0..a7
__device__ __forceinline__ bf16x8 pack8(float a0, float a1, float a2, float a3,
                                        float a4, float a5, float a6, float a7) {
  union { uint u[4]; bf16x8 v; } x;
  x.u[0] = __builtin_amdgcn_perm(__float_as_uint(a1), __float_as_uint(a0), 0x07060302);
  x.u[1] = __builtin_amdgcn_perm(__float_as_uint(a3), __float_as_uint(a2), 0x07060302);
  x.u[2] = __builtin_amdgcn_perm(__float_as_uint(a5), __float_as_uint(a4), 0x07060302);
  x.u[3] = __builtin_amdgcn_perm(__float_as_uint(a7), __float_as_uint(a6), 0x07060302);
  return x.v;
}

// ---------- fp32 -> bf16 convert (X) ----------
__global__ void cvt_bf16_kernel(const float* __restrict__ in, ushort* __restrict__ out, int n4) {
  int i = blockIdx.x * blockDim.x + threadIdx.x;
  if (i >= n4) return;
  float4 f = reinterpret_cast<const float4*>(in)[i];
  ushort4 o;
  o.x = f2bf(f.x); o.y = f2bf(f.y); o.z = f2bf(f.z); o.w = f2bf(f.w);
  reinterpret_cast<ushort4*>(out)[i] = o;
}

// ---------- W[K][N] fp32 -> WT[N][K] bf16; Wq pre-scaled by QSCALE ----------
__global__ void wtrans_kernel(const float* w0, const float* w1, const float* w2, const float* w3,
                              ushort* __restrict__ out) {
  const float* w = (blockIdx.z == 0) ? w0 : (blockIdx.z == 1) ? w1 : (blockIdx.z == 2) ? w2 : w3;
  const float sc = (blockIdx.z == 0) ? QSCALE : 1.0f;
  ushort* o = out + (size_t)blockIdx.z * D_MODEL * D_MODEL;
  __shared__ float tile[32][33];
  int tx = threadIdx.x, ty = threadIdx.y;
  int x = blockIdx.x * 32 + tx;   // n
  int y0 = blockIdx.y * 32;       // k
  #pragma unroll
  for (int i = ty; i < 32; i += 8)
    tile[i][tx] = w[(size_t)(y0 + i) * D_MODEL + x];
  __syncthreads();
  #pragma unroll
  for (int i = ty; i < 32; i += 8)
    o[(size_t)(blockIdx.x * 32 + i) * D_MODEL + y0 + tx] = f2bf(tile[tx][i] * sc);
}

// ---------- concat bq*QSCALE | bk | bv ----------
__global__ void biascat_kernel(const float* __restrict__ bq, const float* __restrict__ bk,
                               const float* __restrict__ bv, float* __restrict__ out) {
  int i = blockIdx.x * 256 + threadIdx.x;
  out[i] = (i < 1024) ? bq[i] * QSCALE : (i < 2048) ? bk[i - 1024] : bv[i - 2048];
}

// ---------- V (cols 2048..3071 of QKV) -> Vt[b][h][d][S], keys permuted per 64-chunk ----------
// Vt col (chunk*64 + c) holds key chunk*64 + g(c); g matches the PV A-frag k-slot order:
// g(c) = (c&32) | ((c&4)<<2) | ((c>>1)&12) | (c&3)
__global__ void vtrans_kernel(const ushort* __restrict__ QKV, ushort* __restrict__ Vt) {
  __shared__ ushort tile[64][TPITCH];
  const int t = threadIdx.x;
  const int ck = blockIdx.x, h = blockIdx.y, b = blockIdx.z;
  {
    int key = t >> 2, ds = (t & 3) * 16;
    const ushort* src = QKV + (size_t)(b * SEQ + ck * 64 + key) * 3072 + 2048 + h * HDIM + ds;
    *(uint4*)&tile[key][ds]     = *(const uint4*)src;
    *(uint4*)&tile[key][ds + 8] = *(const uint4*)(src + 8);
  }
  __syncthreads();
  {
    int d = t >> 2, cg = (t & 3) * 16;
    ushort outv[16];
    #pragma unroll
    for (int i = 0; i < 16; ++i) {
      int c = cg + i;
      int a = (c & 32) | ((c & 4) << 2) | ((c >> 1) & 12) | (c & 3);
      outv[i] = tile[a][d];
    }
    ushort* dst = Vt + (size_t)((b * HEADS + h) * HDIM + d) * SEQ + ck * 64 + cg;
    *(uint4*)dst       = *(uint4*)&outv[0];
    *(uint4*)(dst + 8) = *(uint4*)&outv[8];
  }
}

// ---------- m97-style GEMM: C[M][N] = A[M][K] @ BT[N][K]^T + bias ----------
template <typename OutT>
__global__ __launch_bounds__(256) void gemm_bt(const ushort* __restrict__ A, const ushort* __restrict__ BT,
                                               const float* __restrict__ bias, OutT* __restrict__ C,
                                               int M, int N, int K) {
  __shared__ __align__(16) ushort As[128 * 32];
  __shared__ __align__(16) ushort Bs[128 * 32];
  const int tid  = threadIdx.x;
  const int w    = tid >> 6;
  const int lane = tid & 63;
  const int lo   = lane & 15, quad = lane >> 4;
  const int m0 = blockIdx.y * 128, n0 = blockIdx.x * 128;
  const int ra = lane >> 2;
  const int ca = (lane & 3) * 8;
  const int wm = (w & 1) * 64, wn = (w >> 1) * 64;

  f32x4 acc[4][4];
  #pragma unroll
  for (int i = 0; i < 4; ++i)
    #pragma unroll
    for (int j = 0; j < 4; ++j) acc[i][j] = {0.f, 0.f, 0.f, 0.f};

  for (int k0 = 0; k0 < K; k0 += 32) {
    #pragma unroll
    for (int i = 0; i < 2; ++i) {
      const int j = w * 2 + i;
      gload_lds16(A  + (size_t)(m0 + j * 16 + ra) * K + k0 + ca, &As[j * 512]);
      gload_lds16(BT + (size_t)(n0 + j * 16 + ra) * K + k0 + ca, &Bs[j * 512]);
    }
    __syncthreads();
    bf16x8 af[4], bfv[4];
    #pragma unroll
    for (int mi = 0; mi < 4; ++mi) af[mi]  = *(const bf16x8*)&As[(wm + mi * 16 + lo) * 32 + quad * 8];
    #pragma unroll
    for (int ni = 0; ni < 4; ++ni) bfv[ni] = *(const bf16x8*)&Bs[(wn + ni * 16 + lo) * 32 + quad * 8];
    #pragma unroll
    for (int mi = 0; mi < 4; ++mi)
      #pragma unroll
      for (int ni = 0; ni < 4; ++ni)
        acc[mi][ni] = __builtin_amdgcn_mfma_f32_16x16x32_bf16(af[mi], bfv[ni], acc[mi][ni], 0, 0, 0);
    __syncthreads();
  }

  #pragma unroll
  for (int ni = 0; ni < 4; ++ni) {
    const int col = n0 + wn + ni * 16 + lo;
    const float bv = bias[col];
    #pragma unroll
    for (int mi = 0; mi < 4; ++mi) {
      #pragma unroll
      for (int r = 0; r < 4; ++r) {
        const int row = m0 + wm + mi * 16 + quad * 4 + r;
        float v = acc[mi][ni][r] + bv;
        if constexpr (sizeof(OutT) == 2) C[(size_t)row * N + col] = (OutT)f2bf(v);
        else                             C[(size_t)row * N + col] = v;
      }
    }
  }
}

// ---------- flash attention: block = 128 q rows, wave = 32 q (2 qg x 16), 64-key chunks ----------
// S^T via mfma(A=K,B=Q) -> C-layout lane holds S[q=lo][key=sub*16+quad*4+r]; exp'd values feed
// the PV MFMA A-operand directly from registers (key order matched by vtrans permutation g).
__global__ __launch_bounds__(256, 4) void attn_kernel(const ushort* __restrict__ QKV,
                                                      const ushort* __restrict__ Vt,
                                                      ushort* __restrict__ Og) {
  __shared__ __align__(16) ushort Ks[64 * 64];   // [key][64 d], seg-swizzled
  __shared__ __align__(16) ushort Vs[64 * 64];   // [d][64 key-slots], seg-swizzled

  const int tid  = threadIdx.x;
  const int w    = tid >> 6, lane = tid & 63;
  const int lo   = lane & 15, quad = lane >> 4;
  const int h = blockIdx.y, b = blockIdx.z;
  const int qbase = blockIdx.x * 128 + w * 32;
  const int swz = lo & 7;

  // Q fragments (B-operand layout: n=lo, k=quad*8+j); pre-scaled by QSCALE via Wq
  bf16x8 qf[2][2];
  #pragma unroll
  for (int qg = 0; qg < 2; ++qg) {
    const ushort* qp = QKV + (size_t)(b * SEQ + qbase + qg * 16 + lo) * 3072 + h * HDIM;
    qf[qg][0] = *(const bf16x8*)(qp + quad * 8);
    qf[qg][1] = *(const bf16x8*)(qp + 32 + quad * 8);
  }

  f32x4 acc[2][4];
  #pragma unroll
  for (int qg = 0; qg < 2; ++qg)
    #pragma unroll
    for (int t = 0; t < 4; ++t) acc[qg][t] = {0.f, 0.f, 0.f, 0.f};
  float lsum[2] = {0.f, 0.f};

  for (int ck = 0; ck < SEQ / 64; ++ck) {
    __syncthreads();   // previous chunk fully consumed
    #pragma unroll
    for (int i = 0; i < 2; ++i) {
      const int c16 = (w * 2 + i) * 64 + lane;
      const int r = c16 >> 3, ps = c16 & 7;
      const int gs = ps ^ (r & 7);
      gload_lds16(QKV + (size_t)(b * SEQ + ck * 64 + r) * 3072 + 1024 + h * HDIM + gs * 8,
                  &Ks[(w * 2 + i) * 512]);
      gload_lds16(Vt + (size_t)((b * HEADS + h) * HDIM + r) * SEQ + ck * 64 + gs * 8,
                  &Vs[(w * 2 + i) * 512]);
    }
    __syncthreads();

    // --- phase A: S^T tiles (kf transient per sub) ---
    f32x4 s[2][4];
    #pragma unroll
    for (int qg = 0; qg < 2; ++qg)
      #pragma unroll
      for (int sub = 0; sub < 4; ++sub) s[qg][sub] = {0.f, 0.f, 0.f, 0.f};
    #pragma unroll
    for (int sub = 0; sub < 4; ++sub) {
      const ushort* kr = &Ks[(sub * 16 + lo) * 64];
      bf16x8 k0 = *(const bf16x8*)(kr + ((quad ^ swz) * 8));
      bf16x8 k1 = *(const bf16x8*)(kr + (((4 + quad) ^ swz) * 8));
      #pragma unroll
      for (int qg = 0; qg < 2; ++qg) {
        s[qg][sub] = __builtin_amdgcn_mfma_f32_16x16x32_bf16(k0, qf[qg][0], s[qg][sub], 0, 0, 0);
        s[qg][sub] = __builtin_amdgcn_mfma_f32_16x16x32_bf16(k1, qf[qg][1], s[qg][sub], 0, 0, 0);
      }
    }

    // --- exp + pack A-frags in registers ---
    bf16x8 af[2][2];
    #pragma unroll
    for (int qg = 0; qg < 2; ++qg) {
      float p[4][4];
      #pragma unroll
      for (int sub = 0; sub < 4; ++sub)
        #pragma unroll
        for (int r = 0; r < 4; ++r) p[sub][r] = __builtin_amdgcn_exp2f(s[qg][sub][r]);
      float t0 = 0.f;
      #pragma unroll
      for (int sub = 0; sub < 4; ++sub)
        t0 += (p[sub][0] + p[sub][1]) + (p[sub][2] + p[sub][3]);
      lsum[qg] += t0;
      af[qg][0] = pack8(p[0][0], p[0][1], p[0][2], p[0][3], p[1][0], p[1][1], p[1][2], p[1][3]);
      af[qg][1] = pack8(p[2][0], p[2][1], p[2][2], p[2][3], p[3][0], p[3][1], p[3][2], p[3][3]);
    }

    // --- phase B: PV (A = exp'd scores from registers, B = V^T from LDS) ---
    #pragma unroll
    for (int t = 0; t < 4; ++t) {
      const ushort* vr = &Vs[(t * 16 + lo) * 64];
      #pragma unroll
      for (int hh = 0; hh < 2; ++hh) {
        bf16x8 vf = *(const bf16x8*)(vr + (((hh * 4 + quad) ^ swz) * 8));
        #pragma unroll
        for (int qg = 0; qg < 2; ++qg)
          acc[qg][t] = __builtin_amdgcn_mfma_f32_16x16x32_bf16(af[qg][hh], vf, acc[qg][t], 0, 0, 0);
      }
    }
  }

  // --- epilogue: lsum lives at lane lo = q; reduce across quads, redistribute, store ---
  #pragma unroll
  for (int qg = 0; qg < 2; ++qg) {
    float v = lsum[qg];
    v += __shfl_xor(v, 16);
    v += __shfl_xor(v, 32);
    float linv[4];
    #pragma unroll
    for (int r = 0; r < 4; ++r) linv[r] = 1.0f / __shfl(v, quad * 4 + r);
    #pragma unroll
    for (int t = 0; t < 4; ++t)
      #pragma unroll
      for (int r = 0; r < 4; ++r)
        Og[(size_t)(b * SEQ + qbase + qg * 16 + quad * 4 + r) * D_MODEL + h * HDIM + t * 16 + lo] =
            f2bf(acc[qg][t][r] * linv[r]);
  }
}

extern "C" void kernel_launch(void* const* d_in, const int* in_sizes, int n_in,
                              void* d_out, int out_size, void* d_ws, size_t ws_size,
                              hipStream_t stream) {
  const float* X  = (const float*)d_in[0];
  const float* Wq = (const float*)d_in[1];
  const float* bq = (const float*)d_in[2];
  const float* Wk = (const float*)d_in[3];
  const float* bk = (const float*)d_in[4];
  const float* Wv = (const float*)d_in[5];
  const float* bv = (const float*)d_in[6];
  const float* Wo = (const float*)d_in[7];
  const float* bo = (const float*)d_in[8];
  float* out = (float*)d_out;
  char* ws = (char*)d_ws;

  // workspace (88 MB):
  //   [0,16M)   Xb (bf16 X)  -- later reused as Vt (Xb dead after QKV GEMM)
  //   [16,24M)  WT (4x bf16 transposed weights, q|k|v|o; Wq pre-scaled)
  //   [24,72M)  QKV bf16 [8192][3072]
  //   [72,88M)  O bf16 [8192][1024]; head transiently holds biascat (dead before attn writes O)
  ushort* Xb   = (ushort*)(ws);
  ushort* Vtb  = (ushort*)(ws);
  ushort* WT   = (ushort*)(ws + 16777216);
  ushort* QKVb = (ushort*)(ws + 25165824);
  ushort* Ob   = (ushort*)(ws + 75497472);
  float*  bcat = (float*)(ws + 75497472);
  const int WSTRIDE = D_MODEL * D_MODEL;

  const int n4 = BATCH * SEQ * D_MODEL / 4;
  cvt_bf16_kernel<<<n4 / 256, 256, 0, stream>>>(X, Xb, n4);
  wtrans_kernel<<<dim3(32, 32, 4), dim3(32, 8), 0, stream>>>(Wq, Wk, Wv, Wo, WT);
  biascat_kernel<<<12, 256, 0, stream>>>(bq, bk, bv, bcat);

  // fused QKV projection: [8192,1024] @ [1024,3072] -> QKV bf16
  const int M = BATCH * SEQ;
  gemm_bt<ushort><<<dim3(24, 64), 256, 0, stream>>>(Xb, WT, bcat, QKVb, M, 3 * D_MODEL, D_MODEL);

  // V -> Vt (transposed + PV k-slot key permutation)
  vtrans_kernel<<<dim3(SEQ / 64, HEADS, BATCH), 256, 0, stream>>>(QKVb, Vtb);

  // flash attention
  attn_kernel<<<dim3(SEQ / 128, HEADS, BATCH), 256, 0, stream>>>(QKVb, Vtb, Ob);

  // output projection (fp32 out + bias)
  gemm_bt<float><<<dim3(8, 64), 256, 0, stream>>>(Ob, WT + 3 * WSTRIDE, bo, out, M, D_MODEL, D_MODEL);
}

// Round 4
// 272.053 us; speedup vs baseline: 2.0605x; 1.0867x over previous
//
#include <hip/hip_runtime.h>
#include <stdint.h>

typedef __attribute__((ext_vector_type(8))) short bf16x8;   // 8 bf16 in 4 VGPRs
typedef __attribute__((ext_vector_type(4))) float f32x4;
typedef __attribute__((address_space(1))) void as1_void;
typedef __attribute__((address_space(3))) void as3_void;

#define D_MODEL 1024
#define SEQ     2048
#define BATCH   4
#define HEADS   16
#define HDIM    64

// softmax scale: exp(s/32) = exp2(s * log2e/32); folded into Wq/bq at prep time
#define QSCALE 0.045084220029218407f

__device__ __forceinline__ ushort f2bf(float f) {
  union { float f; unsigned u; } v; v.f = f;
  unsigned u = v.u + 0x7fffu + ((v.u >> 16) & 1u);  // RNE
  return (ushort)(u >> 16);
}

__device__ __forceinline__ void gload_lds16(const void* g, void* l) {
  // width=16: emits global_load_lds_dwordx4; LDS dest = wave-uniform base + lane*16
  __builtin_amdgcn_global_load_lds((as1_void*)(uintptr_t)g, (as3_void*)l, 16, 0, 0);
}

// pack 8 floats -> bf16x8 (truncation) via v_perm
__device__ __forceinline__ bf16x8 pack8(float a0, float a1, float a2, float a3,
                                        float a4, float a5, float a6, float a7) {
  union { uint u[4]; bf16x8 v; } x;
  x.u[0] = __builtin_amdgcn_perm(__float_as_uint(a1), __float_as_uint(a0), 0x07060302);
  x.u[1] = __builtin_amdgcn_perm(__float_as_uint(a3), __float_as_uint(a2), 0x07060302);
  x.u[2] = __builtin_amdgcn_perm(__float_as_uint(a5), __float_as_uint(a4), 0x07060302);
  x.u[3] = __builtin_amdgcn_perm(__float_as_uint(a7), __float_as_uint(a6), 0x07060302);
  return x.v;
}

// ---------- fused prep: X->bf16 | W transpose->bf16 (Wq scaled) | bias concat ----------
__global__ void prep_kernel(const float* __restrict__ X,
                            const float* w0, const float* w1, const float* w2, const float* w3,
                            const float* __restrict__ bq, const float* __restrict__ bk,
                            const float* __restrict__ bv,
                            ushort* __restrict__ Xb, ushort* __restrict__ WT,
                            float* __restrict__ bcat) {
  __shared__ float tile[32][33];
  const int bx = blockIdx.x, t = threadIdx.x;
  if (bx < 8192) {                       // X fp32 -> bf16, 8192*256 float4 groups
    int i = bx * 256 + t;
    float4 f = reinterpret_cast<const float4*>(X)[i];
    ushort4 o;
    o.x = f2bf(f.x); o.y = f2bf(f.y); o.z = f2bf(f.z); o.w = f2bf(f.w);
    reinterpret_cast<ushort4*>(Xb)[i] = o;
  } else if (bx < 12288) {               // weight transpose: 4 weights x 1024 tiles
    int tz = bx - 8192;
    int z = tz >> 10;
    int xy = tz & 1023;
    int bxt = xy & 31, byt = xy >> 5;
    const float* w = (z == 0) ? w0 : (z == 1) ? w1 : (z == 2) ? w2 : w3;
    const float sc = (z == 0) ? QSCALE : 1.0f;
    ushort* o = WT + (size_t)z * D_MODEL * D_MODEL;
    int tx = t & 31, ty = t >> 5;
    int x = bxt * 32 + tx;
    int y0 = byt * 32;
    #pragma unroll
    for (int i = ty; i < 32; i += 8)
      tile[i][tx] = w[(size_t)(y0 + i) * D_MODEL + x];
    __syncthreads();
    #pragma unroll
    for (int i = ty; i < 32; i += 8)
      o[(size_t)(bxt * 32 + i) * D_MODEL + y0 + tx] = f2bf(tile[tx][i] * sc);
  } else {                               // bias concat (12 blocks)
    int i = (bx - 12288) * 256 + t;
    bcat[i] = (i < 1024) ? bq[i] * QSCALE : (i < 2048) ? bk[i - 1024] : bv[i - 2048];
  }
}

// ---------- QKV GEMM: [8192,1024]@[1024,3072]; Q,K -> QK[8192][2048]; V -> Vt (permuted transpose) ----------
// Vt[b][h][d][S], col (ck*64+c) holds key ck*64+g(c), g(c)=(c&32)|((c&4)<<2)|((c>>1)&12)|(c&3)
// (inverse used here: c = (key&32) | (quad<<3) | ((key&16)>>2) | r for key = base|quad*4+r)
__global__ __launch_bounds__(256) void gemm_qkv(const ushort* __restrict__ A, const ushort* __restrict__ BT,
                                                const float* __restrict__ bias,
                                                ushort* __restrict__ QK, ushort* __restrict__ Vt) {
  __shared__ __align__(16) ushort As[128 * 32];
  __shared__ __align__(16) ushort Bs[128 * 32];
  const int K = D_MODEL;
  const int tid  = threadIdx.x;
  const int w    = tid >> 6;
  const int lane = tid & 63;
  const int lo   = lane & 15, quad = lane >> 4;
  const int m0 = blockIdx.y * 128, n0 = blockIdx.x * 128;
  const int ra = lane >> 2;
  const int ca = (lane & 3) * 8;
  const int wm = (w & 1) * 64, wn = (w >> 1) * 64;

  f32x4 acc[4][4];
  #pragma unroll
  for (int i = 0; i < 4; ++i)
    #pragma unroll
    for (int j = 0; j < 4; ++j) acc[i][j] = {0.f, 0.f, 0.f, 0.f};

  for (int k0 = 0; k0 < K; k0 += 32) {
    #pragma unroll
    for (int i = 0; i < 2; ++i) {
      const int j = w * 2 + i;
      gload_lds16(A  + (size_t)(m0 + j * 16 + ra) * K + k0 + ca, &As[j * 512]);
      gload_lds16(BT + (size_t)(n0 + j * 16 + ra) * K + k0 + ca, &Bs[j * 512]);
    }
    __syncthreads();
    bf16x8 af[4], bfv[4];
    #pragma unroll
    for (int mi = 0; mi < 4; ++mi) af[mi]  = *(const bf16x8*)&As[(wm + mi * 16 + lo) * 32 + quad * 8];
    #pragma unroll
    for (int ni = 0; ni < 4; ++ni) bfv[ni] = *(const bf16x8*)&Bs[(wn + ni * 16 + lo) * 32 + quad * 8];
    #pragma unroll
    for (int mi = 0; mi < 4; ++mi)
      #pragma unroll
      for (int ni = 0; ni < 4; ++ni)
        acc[mi][ni] = __builtin_amdgcn_mfma_f32_16x16x32_bf16(af[mi], bfv[ni], acc[mi][ni], 0, 0, 0);
    __syncthreads();
  }

  if (blockIdx.x < 16) {
    // Q,K part: dense [8192][2048] store
    #pragma unroll
    for (int ni = 0; ni < 4; ++ni) {
      const int col = n0 + wn + ni * 16 + lo;
      const float bv = bias[col];
      #pragma unroll
      for (int mi = 0; mi < 4; ++mi) {
        #pragma unroll
        for (int r = 0; r < 4; ++r) {
          const int row = m0 + wm + mi * 16 + quad * 4 + r;
          QK[(size_t)row * 2048 + col] = f2bf(acc[mi][ni][r] + bv);
        }
      }
    }
  } else {
    // V part: permuted-transpose store into Vt[b][h][d][SEQ]
    #pragma unroll
    for (int ni = 0; ni < 4; ++ni) {
      const int col  = n0 + wn + ni * 16 + lo;
      const int vcol = col - 2048;
      const int hh = vcol >> 6, d = vcol & 63;
      const float bv = bias[col];
      #pragma unroll
      for (int mi = 0; mi < 4; ++mi) {
        const int base = m0 + wm + mi * 16;              // multiple of 16
        const int brow = base + quad * 4;                // 4 keys brow..brow+3
        const int bidx = brow >> 11;                     // batch
        const int srow = brow & 2047;                    // seq within batch
        const int ck   = srow >> 6;
        const int c0   = (base & 32) + (quad << 3) + ((base >> 2) & 4);
        ushort e0 = f2bf(acc[mi][ni][0] + bv);
        ushort e1 = f2bf(acc[mi][ni][1] + bv);
        ushort e2 = f2bf(acc[mi][ni][2] + bv);
        ushort e3 = f2bf(acc[mi][ni][3] + bv);
        uint2 pk;
        pk.x = (uint)e0 | ((uint)e1 << 16);
        pk.y = (uint)e2 | ((uint)e3 << 16);
        *(uint2*)&Vt[(size_t)((bidx * HEADS + hh) * HDIM + d) * SEQ + ck * 64 + c0] = pk;
      }
    }
  }
}

// ---------- m97-style GEMM (final projection): C[M][N] = A@BT^T + bias, fp32 out ----------
__global__ __launch_bounds__(256) void gemm_bt_f32(const ushort* __restrict__ A, const ushort* __restrict__ BT,
                                                   const float* __restrict__ bias, float* __restrict__ C,
                                                   int M, int N, int K) {
  __shared__ __align__(16) ushort As[128 * 32];
  __shared__ __align__(16) ushort Bs[128 * 32];
  const int tid  = threadIdx.x;
  const int w    = tid >> 6;
  const int lane = tid & 63;
  const int lo   = lane & 15, quad = lane >> 4;
  const int m0 = blockIdx.y * 128, n0 = blockIdx.x * 128;
  const int ra = lane >> 2;
  const int ca = (lane & 3) * 8;
  const int wm = (w & 1) * 64, wn = (w >> 1) * 64;

  f32x4 acc[4][4];
  #pragma unroll
  for (int i = 0; i < 4; ++i)
    #pragma unroll
    for (int j = 0; j < 4; ++j) acc[i][j] = {0.f, 0.f, 0.f, 0.f};

  for (int k0 = 0; k0 < K; k0 += 32) {
    #pragma unroll
    for (int i = 0; i < 2; ++i) {
      const int j = w * 2 + i;
      gload_lds16(A  + (size_t)(m0 + j * 16 + ra) * K + k0 + ca, &As[j * 512]);
      gload_lds16(BT + (size_t)(n0 + j * 16 + ra) * K + k0 + ca, &Bs[j * 512]);
    }
    __syncthreads();
    bf16x8 af[4], bfv[4];
    #pragma unroll
    for (int mi = 0; mi < 4; ++mi) af[mi]  = *(const bf16x8*)&As[(wm + mi * 16 + lo) * 32 + quad * 8];
    #pragma unroll
    for (int ni = 0; ni < 4; ++ni) bfv[ni] = *(const bf16x8*)&Bs[(wn + ni * 16 + lo) * 32 + quad * 8];
    #pragma unroll
    for (int mi = 0; mi < 4; ++mi)
      #pragma unroll
      for (int ni = 0; ni < 4; ++ni)
        acc[mi][ni] = __builtin_amdgcn_mfma_f32_16x16x32_bf16(af[mi], bfv[ni], acc[mi][ni], 0, 0, 0);
    __syncthreads();
  }

  #pragma unroll
  for (int ni = 0; ni < 4; ++ni) {
    const int col = n0 + wn + ni * 16 + lo;
    const float bv = bias[col];
    #pragma unroll
    for (int mi = 0; mi < 4; ++mi) {
      #pragma unroll
      for (int r = 0; r < 4; ++r) {
        const int row = m0 + wm + mi * 16 + quad * 4 + r;
        C[(size_t)row * N + col] = acc[mi][ni][r] + bv;
      }
    }
  }
}

// ---------- flash attention: block = 256 q rows, wave = 64 q (4 qg x 16), 64-key chunks ----------
// S^T via mfma(A=K,B=Q); exp'd scores feed PV A-operand directly from registers
// (key order matched by the Vt store permutation in gemm_qkv).
__global__ __launch_bounds__(256, 2) void attn_kernel(const ushort* __restrict__ QK,
                                                      const ushort* __restrict__ Vt,
                                                      ushort* __restrict__ Og) {
  __shared__ __align__(16) ushort Ks[64 * 64];   // [key][64 d], seg-swizzled
  __shared__ __align__(16) ushort Vs[64 * 64];   // [d][64 key-slots], seg-swizzled

  const int tid  = threadIdx.x;
  const int w    = tid >> 6, lane = tid & 63;
  const int lo   = lane & 15, quad = lane >> 4;
  const int h = blockIdx.y, b = blockIdx.z;
  const int qbase = blockIdx.x * 256 + w * 64;
  const int swz = lo & 7;

  // Q fragments (B-operand layout: n=lo, k=quad*8+j); pre-scaled by QSCALE via Wq
  bf16x8 qf[4][2];
  #pragma unroll
  for (int qg = 0; qg < 4; ++qg) {
    const ushort* qp = QK + (size_t)(b * SEQ + qbase + qg * 16 + lo) * 2048 + h * HDIM;
    qf[qg][0] = *(const bf16x8*)(qp + quad * 8);
    qf[qg][1] = *(const bf16x8*)(qp + 32 + quad * 8);
  }

  f32x4 acc[4][4];
  #pragma unroll
  for (int qg = 0; qg < 4; ++qg)
    #pragma unroll
    for (int t = 0; t < 4; ++t) acc[qg][t] = {0.f, 0.f, 0.f, 0.f};
  float lsum[4] = {0.f, 0.f, 0.f, 0.f};

  for (int ck = 0; ck < SEQ / 64; ++ck) {
    __syncthreads();   // previous chunk fully consumed
    #pragma unroll
    for (int i = 0; i < 2; ++i) {
      const int c16 = (w * 2 + i) * 64 + lane;
      const int r = c16 >> 3, ps = c16 & 7;
      const int gs = ps ^ (r & 7);
      gload_lds16(QK + (size_t)(b * SEQ + ck * 64 + r) * 2048 + 1024 + h * HDIM + gs * 8,
                  &Ks[(w * 2 + i) * 512]);
      gload_lds16(Vt + (size_t)((b * HEADS + h) * HDIM + r) * SEQ + ck * 64 + gs * 8,
                  &Vs[(w * 2 + i) * 512]);
    }
    __syncthreads();

    // --- phase A: K fragments resident, S^T per q-group, exp + pack in registers ---
    bf16x8 kf[4][2];
    #pragma unroll
    for (int sub = 0; sub < 4; ++sub) {
      const ushort* kr = &Ks[(sub * 16 + lo) * 64];
      kf[sub][0] = *(const bf16x8*)(kr + ((quad ^ swz) * 8));
      kf[sub][1] = *(const bf16x8*)(kr + (((4 + quad) ^ swz) * 8));
    }

    bf16x8 af[4][2];
    #pragma unroll
    for (int qg = 0; qg < 4; ++qg) {
      f32x4 s[4];
      #pragma unroll
      for (int sub = 0; sub < 4; ++sub) s[sub] = {0.f, 0.f, 0.f, 0.f};
      #pragma unroll
      for (int sub = 0; sub < 4; ++sub) {
        s[sub] = __builtin_amdgcn_mfma_f32_16x16x32_bf16(kf[sub][0], qf[qg][0], s[sub], 0, 0, 0);
        s[sub] = __builtin_amdgcn_mfma_f32_16x16x32_bf16(kf[sub][1], qf[qg][1], s[sub], 0, 0, 0);
      }
      float p[4][4];
      #pragma unroll
      for (int sub = 0; sub < 4; ++sub)
        #pragma unroll
        for (int r = 0; r < 4; ++r) p[sub][r] = __builtin_amdgcn_exp2f(s[sub][r]);
      float t0 = 0.f;
      #pragma unroll
      for (int sub = 0; sub < 4; ++sub)
        t0 += (p[sub][0] + p[sub][1]) + (p[sub][2] + p[sub][3]);
      lsum[qg] += t0;
      af[qg][0] = pack8(p[0][0], p[0][1], p[0][2], p[0][3], p[1][0], p[1][1], p[1][2], p[1][3]);
      af[qg][1] = pack8(p[2][0], p[2][1], p[2][2], p[2][3], p[3][0], p[3][1], p[3][2], p[3][3]);
    }

    // --- phase B: PV (A = exp'd scores from registers, B = V^T from LDS) ---
    #pragma unroll
    for (int t = 0; t < 4; ++t) {
      const ushort* vr = &Vs[(t * 16 + lo) * 64];
      #pragma unroll
      for (int hh = 0; hh < 2; ++hh) {
        bf16x8 vf = *(const bf16x8*)(vr + (((hh * 4 + quad) ^ swz) * 8));
        #pragma unroll
        for (int qg = 0; qg < 4; ++qg)
          acc[qg][t] = __builtin_amdgcn_mfma_f32_16x16x32_bf16(af[qg][hh], vf, acc[qg][t], 0, 0, 0);
      }
    }
  }

  // --- epilogue: lsum lives at lane lo = q; reduce across quads, redistribute, store ---
  #pragma unroll
  for (int qg = 0; qg < 4; ++qg) {
    float v = lsum[qg];
    v += __shfl_xor(v, 16);
    v += __shfl_xor(v, 32);
    float linv[4];
    #pragma unroll
    for (int r = 0; r < 4; ++r) linv[r] = 1.0f / __shfl(v, quad * 4 + r);
    #pragma unroll
    for (int t = 0; t < 4; ++t)
      #pragma unroll
      for (int r = 0; r < 4; ++r)
        Og[(size_t)(b * SEQ + qbase + qg * 16 + quad * 4 + r) * D_MODEL + h * HDIM + t * 16 + lo] =
            f2bf(acc[qg][t][r] * linv[r]);
  }
}

extern "C" void kernel_launch(void* const* d_in, const int* in_sizes, int n_in,
                              void* d_out, int out_size, void* d_ws, size_t ws_size,
                              hipStream_t stream) {
  const float* X  = (const float*)d_in[0];
  const float* Wq = (const float*)d_in[1];
  const float* bq = (const float*)d_in[2];
  const float* Wk = (const float*)d_in[3];
  const float* bk = (const float*)d_in[4];
  const float* Wv = (const float*)d_in[5];
  const float* bv = (const float*)d_in[6];
  const float* Wo = (const float*)d_in[7];
  const float* bo = (const float*)d_in[8];
  float* out = (float*)d_out;
  char* ws = (char*)d_ws;

  // workspace (88 MB):
  //   [0,16M)   Xb  (bf16 X)
  //   [16,24M)  WT  (4x bf16 transposed weights q|k|v|o; Wq pre-scaled)
  //   [24,56M)  QK  bf16 [8192][2048]
  //   [56,72M)  Vt  bf16 [b][h][64][2048] (permuted keys)
  //   [72,88M)  Ob  bf16 [8192][1024]; head transiently holds bcat (dead before attn writes Ob)
  ushort* Xb  = (ushort*)(ws);
  ushort* WT  = (ushort*)(ws + 16777216);
  ushort* QKb = (ushort*)(ws + 25165824);
  ushort* Vtb = (ushort*)(ws + 58720256);
  ushort* Ob  = (ushort*)(ws + 75497472);
  float*  bcat = (float*)(ws + 75497472);
  const int WSTRIDE = D_MODEL * D_MODEL;

  // 1) fused prep: X->bf16, weight transposes, bias concat
  prep_kernel<<<12300, 256, 0, stream>>>(X, Wq, Wk, Wv, Wo, bq, bk, bv, Xb, WT, bcat);

  // 2) fused QKV projection; V written straight to Vt (permuted transpose)
  gemm_qkv<<<dim3(24, 64), 256, 0, stream>>>(Xb, WT, bcat, QKb, Vtb);

  // 3) flash attention
  attn_kernel<<<dim3(SEQ / 256, HEADS, BATCH), 256, 0, stream>>>(QKb, Vtb, Ob);

  // 4) output projection (fp32 out + bias)
  gemm_bt_f32<<<dim3(8, 64), 256, 0, stream>>>(Ob, WT + 3 * WSTRIDE, bo, out,
                                               BATCH * SEQ, D_MODEL, D_MODEL);
}